// Round 3
// baseline (2088.180 us; speedup 1.0000x reference)
//
#include <hip/hip_runtime.h>

// Problem constants (match reference)
static constexpr int kNE  = 200000;   // entities
static constexpr int kEP  = 1000000;  // profile edges (review -> entity)
static constexpr int kEU  = 1000000;  // purchased edges (entity -> entity)
static constexpr int kD   = 192;      // 64 + 128
static constexpr int kC4  = 48;       // float4 chunks per 192-f32 row

static constexpr int TPB = 256;
static constexpr int kScanChunk = 512;
static constexpr int kNBlkScan  = (kNE + kScanChunk - 1) / kScanChunk;  // 391
static constexpr int kAlignNE   = 200064;  // padded N_E for int arrays

static inline int grid_for(long long work) {
  long long b = (work + TPB - 1) / TPB;
  return (int)(b < 2048 ? b : 2048);
}

// ---------- CSR build: histogram ----------
__global__ void k_count(const int* __restrict__ prof_dst,
                        const int* __restrict__ pur_src,
                        const int* __restrict__ pur_dst,
                        int* __restrict__ cnt_p, int* __restrict__ cnt_u) {
  int stride = gridDim.x * blockDim.x;
  for (int i = blockIdx.x * blockDim.x + threadIdx.x; i < kEP; i += stride)
    atomicAdd(&cnt_p[prof_dst[i]], 1);
  for (int i = blockIdx.x * blockDim.x + threadIdx.x; i < kEU; i += stride) {
    atomicAdd(&cnt_u[pur_src[i]], 1);
    atomicAdd(&cnt_u[pur_dst[i]], 1);
  }
}

// ---------- CSR build: 3-phase exclusive scan (200K ints -> offs[N+1]) ----------
__global__ void k_scan_a(const int* __restrict__ cnt, int* __restrict__ bsum) {
  __shared__ int s[TPB];
  int b = blockIdx.x, t = threadIdx.x;
  int base = b * kScanChunk;
  int v = 0;
  for (int i = t; i < kScanChunk; i += TPB) {
    int idx = base + i;
    v += (idx < kNE) ? cnt[idx] : 0;
  }
  s[t] = v; __syncthreads();
  for (int w = TPB / 2; w > 0; w >>= 1) {
    if (t < w) s[t] += s[t + w];
    __syncthreads();
  }
  if (t == 0) bsum[b] = s[0];
}

__global__ void k_scan_b(int* __restrict__ bsum) {
  if (threadIdx.x == 0 && blockIdx.x == 0) {
    int acc = 0;
    for (int i = 0; i < kNBlkScan; i++) { int t = bsum[i]; bsum[i] = acc; acc += t; }
  }
}

__global__ void k_scan_c(const int* __restrict__ cnt, const int* __restrict__ bsum,
                         int* __restrict__ offs) {
  int b = blockIdx.x;
  if (threadIdx.x != 0) return;
  int base = b * kScanChunk;
  int acc = bsum[b];
  int end = base + kScanChunk; if (end > kNE) end = kNE;
  for (int i = base; i < end; i++) { offs[i] = acc; acc += cnt[i]; }
  if (end == kNE) offs[kNE] = acc;
}

// ---------- CSR build: fill edge lists via per-entity cursors ----------
// plist[v]: review sources of profile in-edges.
// ulist[v]: packed (idx<<1)|flag. flag=0: idx = purchased edge id (in-edge at dst);
//           flag=1: idx = neighbor d (out-edge at src, contributes e[d]*inv[d]).
__global__ void k_fill(const int* __restrict__ prof_src, const int* __restrict__ prof_dst,
                       const int* __restrict__ pur_src, const int* __restrict__ pur_dst,
                       const int* __restrict__ offs_p, const int* __restrict__ offs_u,
                       int* __restrict__ cur_p, int* __restrict__ cur_u,
                       int* __restrict__ plist, int* __restrict__ ulist) {
  int stride = gridDim.x * blockDim.x;
  for (int i = blockIdx.x * blockDim.x + threadIdx.x; i < kEP; i += stride) {
    int d = prof_dst[i];
    int pos = offs_p[d] + atomicAdd(&cur_p[d], 1);
    plist[pos] = prof_src[i];
  }
  for (int i = blockIdx.x * blockDim.x + threadIdx.x; i < kEU; i += stride) {
    int s = pur_src[i], d = pur_dst[i];
    int pa = offs_u[d] + atomicAdd(&cur_u[d], 1);
    ulist[pa] = (i << 1);            // in-entry at d carries edge id
    int pb = offs_u[s] + atomicAdd(&cur_u[s], 1);
    ulist[pb] = (d << 1) | 1;        // out-entry at s carries neighbor
  }
}

// ---------- e0: pull review_h onto entities, concat entity_l, write e_buf+out,
// and compute inv[v] = 1/sqrt(max(deg_i,1)). 64 threads/entity, 48 active. ----------
__global__ void k_prof_pull(const float4* __restrict__ entity_l,
                            const float4* __restrict__ review_h,
                            const int* __restrict__ plist,
                            const int* __restrict__ offs_p,
                            const int* __restrict__ offs_u,
                            float* __restrict__ inv,
                            float4* __restrict__ e_buf,
                            float4* __restrict__ out) {
  const long long total = (long long)kNE * 64;
  long long stride = (long long)gridDim.x * blockDim.x;
  for (long long t = (long long)blockIdx.x * blockDim.x + threadIdx.x; t < total;
       t += stride) {
    int v = (int)(t >> 6);
    int c = (int)(t & 63);
    if (c == 0) {
      int du = offs_u[v + 1] - offs_u[v];
      inv[v] = 1.0f / sqrtf((float)(du > 1 ? du : 1));
    }
    if (c >= kC4) continue;
    float4 r;
    if (c < 16) {
      r = entity_l[v * 16 + c];
    } else {
      int o0 = offs_p[v], o1 = offs_p[v + 1];
      float ax = 0, ay = 0, az = 0, aw = 0;
      for (int j = o0; j < o1; j++) {
        int rr = plist[j];
        float4 h = review_h[(long long)rr * 32 + (c - 16)];
        ax += h.x; ay += h.y; az += h.z; aw += h.w;
      }
      float dp = (float)((o1 - o0) > 1 ? (o1 - o0) : 1);
      r.x = ax / dp; r.y = ay / dp; r.z = az / dp; r.w = aw / dp;
    }
    e_buf[(long long)v * kC4 + c] = r;
    out[(long long)v * kC4 + c] = r;
  }
}

// ---------- one conv hop, pull form, fused epilogue ----------
// e_new[v] = inv[v] * ( sum_in (e[s] + q_e0[q]*inv[s]) + sum_out e[d]*inv[d] )
// out = (out + e_new) * rdiv   (1 mid-loop, 1/3 final)
__global__ void k_conv_pull(const float4* __restrict__ e,
                            const float4* __restrict__ q_e0,
                            const int* __restrict__ ulist,
                            const int* __restrict__ offs_u,
                            const int* __restrict__ pur_src,
                            const int* __restrict__ q_id,
                            const float* __restrict__ inv,
                            float4* __restrict__ e_next,
                            float4* __restrict__ out,
                            float rdiv) {
  const long long total = (long long)kNE * 64;
  long long stride = (long long)gridDim.x * blockDim.x;
  for (long long t = (long long)blockIdx.x * blockDim.x + threadIdx.x; t < total;
       t += stride) {
    int v = (int)(t >> 6);
    int c = (int)(t & 63);
    if (c >= kC4) continue;
    int o0 = offs_u[v], o1 = offs_u[v + 1];
    float ax = 0, ay = 0, az = 0, aw = 0;
    for (int j = o0; j < o1; j++) {
      int ent = ulist[j];
      int idx = ent >> 1;
      if (ent & 1) {  // out-edge: e[d]*inv[d]
        float iv = inv[idx];
        float4 ed = e[(long long)idx * kC4 + c];
        ax += ed.x * iv; ay += ed.y * iv; az += ed.z * iv; aw += ed.w * iv;
      } else {        // in-edge (edge id): e[s] + q_e0[q]*inv[s]
        int s = pur_src[idx];
        int q = q_id[idx];
        float iv = inv[s];
        float4 es = e[(long long)s * kC4 + c];
        float4 qv = q_e0[(long long)q * kC4 + c];
        ax += es.x + qv.x * iv; ay += es.y + qv.y * iv;
        az += es.z + qv.z * iv; aw += es.w + qv.w * iv;
      }
    }
    float ivv = inv[v];
    float4 en = {ax * ivv, ay * ivv, az * ivv, aw * ivv};
    e_next[(long long)v * kC4 + c] = en;
    float4 o = out[(long long)v * kC4 + c];
    o.x = (o.x + en.x) * rdiv; o.y = (o.y + en.y) * rdiv;
    o.z = (o.z + en.z) * rdiv; o.w = (o.w + en.w) * rdiv;
    out[(long long)v * kC4 + c] = o;
  }
}

extern "C" void kernel_launch(void* const* d_in, const int* in_sizes, int n_in,
                              void* d_out, int out_size, void* d_ws, size_t ws_size,
                              hipStream_t stream) {
  const float4* entity_l = (const float4*)d_in[0];
  const float4* review_h = (const float4*)d_in[1];
  const float4* query_e0 = (const float4*)d_in[2];
  const int* prof_src = (const int*)d_in[3];
  const int* prof_dst = (const int*)d_in[4];
  const int* pur_src  = (const int*)d_in[5];
  const int* pur_dst  = (const int*)d_in[6];
  const int* q_id     = (const int*)d_in[7];

  const size_t row_floats = (size_t)kNE * kD;     // 38.4M floats
  float* B0     = (float*)d_ws;                   // e ping      (153.6 MB)
  float* B1     = B0 + row_floats;                // e pong      (153.6 MB)
  int* cnt_p    = (int*)(B1 + row_floats);
  int* cnt_u    = cnt_p + kAlignNE;
  int* offs_p   = cnt_u + kAlignNE;               // kNE+1 used
  int* offs_u   = offs_p + kAlignNE;
  int* cur_p    = offs_u + kAlignNE;
  int* cur_u    = cur_p + kAlignNE;
  int* bsum     = cur_u + kAlignNE;               // 391 used (reused for both scans)
  float* inv    = (float*)(bsum + 512);
  int* plist    = (int*)(inv + kAlignNE);         // 1M
  int* ulist    = plist + kEP;                    // 2M
  // total ~324 MB

  // zero the histogram + cursor arrays (ws is re-poisoned before every call)
  hipMemsetAsync(cnt_p, 0, 2 * kAlignNE * sizeof(int), stream);
  hipMemsetAsync(cur_p, 0, 2 * kAlignNE * sizeof(int), stream);

  k_count<<<grid_for(kEU), TPB, 0, stream>>>(prof_dst, pur_src, pur_dst, cnt_p, cnt_u);

  // exclusive scans -> offsets (bsum reused; launches are stream-ordered)
  k_scan_a<<<kNBlkScan, TPB, 0, stream>>>(cnt_p, bsum);
  k_scan_b<<<1, 64, 0, stream>>>(bsum);
  k_scan_c<<<kNBlkScan, 64, 0, stream>>>(cnt_p, bsum, offs_p);
  k_scan_a<<<kNBlkScan, TPB, 0, stream>>>(cnt_u, bsum);
  k_scan_b<<<1, 64, 0, stream>>>(bsum);
  k_scan_c<<<kNBlkScan, 64, 0, stream>>>(cnt_u, bsum, offs_u);

  k_fill<<<grid_for(kEU), TPB, 0, stream>>>(prof_src, prof_dst, pur_src, pur_dst,
                                            offs_p, offs_u, cur_p, cur_u, plist, ulist);

  // e0 (B0) + out init + inv
  k_prof_pull<<<grid_for((long long)kNE * 64), TPB, 0, stream>>>(
      entity_l, review_h, plist, offs_p, offs_u, inv, (float4*)B0, (float4*)d_out);

  // hop 1: B0 -> B1 ; hop 2: B1 -> B0 (final average /3)
  k_conv_pull<<<grid_for((long long)kNE * 64), TPB, 0, stream>>>(
      (const float4*)B0, query_e0, ulist, offs_u, pur_src, q_id, inv,
      (float4*)B1, (float4*)d_out, 1.0f);
  k_conv_pull<<<grid_for((long long)kNE * 64), TPB, 0, stream>>>(
      (const float4*)B1, query_e0, ulist, offs_u, pur_src, q_id, inv,
      (float4*)B0, (float4*)d_out, 1.0f / 3.0f);
}

// Round 6
// 1839.799 us; speedup vs baseline: 1.1350x; 1.1350x over previous
//
#include <hip/hip_runtime.h>

// Problem constants (match reference)
static constexpr int kNE  = 200000;   // entities
static constexpr int kEP  = 1000000;  // profile edges (review -> entity)
static constexpr int kEU  = 1000000;  // purchased edges (entity -> entity)
static constexpr int kD   = 192;      // 64 + 128 floats per row
static constexpr int kC4  = 48;       // float4 chunks per row

static constexpr int TPB    = 256;
static constexpr int kChunk = 256;                              // scan chunk
static constexpr int kNBlk  = (kNE + kChunk - 1) / kChunk;      // 782
static constexpr int kAlignNE = 200064;                         // padded N_E

static inline int grid_for(long long work) {
  long long b = (work + TPB - 1) / TPB;
  return (int)(b < 2048 ? b : 2048);
}

// ---------- histograms: prof in-deg, purchased in-deg, purchased out-deg ----------
__global__ void k_count3(const int* __restrict__ prof_dst,
                         const int* __restrict__ pur_src,
                         const int* __restrict__ pur_dst,
                         int* __restrict__ cnt3) {
  int* cp = cnt3;
  int* ci = cnt3 + kAlignNE;
  int* co = cnt3 + 2 * kAlignNE;
  int stride = gridDim.x * blockDim.x;
  for (int i = blockIdx.x * blockDim.x + threadIdx.x; i < kEP; i += stride)
    atomicAdd(&cp[prof_dst[i]], 1);
  for (int i = blockIdx.x * blockDim.x + threadIdx.x; i < kEU; i += stride) {
    atomicAdd(&ci[pur_dst[i]], 1);
    atomicAdd(&co[pur_src[i]], 1);
  }
}

// ---------- scan phase A: per-block sums (grid.y = which array) ----------
__global__ void k_scan_a3(const int* __restrict__ cnt3, int* __restrict__ bsum3) {
  int a = blockIdx.y;
  const int* cnt = cnt3 + a * kAlignNE;
  int idx = blockIdx.x * kChunk + threadIdx.x;
  int v = (idx < kNE) ? cnt[idx] : 0;
  __shared__ int s[TPB];
  s[threadIdx.x] = v; __syncthreads();
  for (int w = TPB / 2; w > 0; w >>= 1) {
    if (threadIdx.x < w) s[threadIdx.x] += s[threadIdx.x + w];
    __syncthreads();
  }
  if (threadIdx.x == 0) bsum3[a * kNBlk + blockIdx.x] = s[0];
}

// ---------- scan phase B: exclusive-scan the block sums (3 waves, 1/array) ----------
__global__ void k_scan_b3(int* __restrict__ bsum3) {
  int a = threadIdx.x >> 6;     // wave id = array id (blockDim = 192)
  int lane = threadIdx.x & 63;
  int* b = bsum3 + a * kNBlk;
  int carry = 0;
  for (int base = 0; base < kNBlk; base += 64) {
    int i = base + lane;
    int val = (i < kNBlk) ? b[i] : 0;
    int x = val;
    for (int off = 1; off < 64; off <<= 1) {
      int y = __shfl_up(x, off);
      if (lane >= off) x += y;
    }
    int tot = __shfl(x, 63);
    if (i < kNBlk) b[i] = carry + x - val;   // exclusive
    carry += tot;
  }
}

// ---------- scan phase C: per-element exclusive offsets ----------
__global__ void k_scan_c3(const int* __restrict__ cnt3, const int* __restrict__ bsum3,
                          int* __restrict__ offs3) {
  int a = blockIdx.y;
  const int* cnt = cnt3 + a * kAlignNE;
  int* offs = offs3 + a * kAlignNE;
  int idx = blockIdx.x * kChunk + threadIdx.x;
  int val = (idx < kNE) ? cnt[idx] : 0;
  int lane = threadIdx.x & 63, w = threadIdx.x >> 6;
  int x = val;
  for (int off = 1; off < 64; off <<= 1) {
    int y = __shfl_up(x, off);
    if (lane >= off) x += y;
  }
  __shared__ int ws[4];
  if (lane == 63) ws[w] = x;
  __syncthreads();
  int add = 0;
  for (int i = 0; i < w; i++) add += ws[i];
  int excl = bsum3[a * kNBlk + blockIdx.x] + add + x - val;
  if (idx < kNE) offs[idx] = excl;
  if (idx == kNE - 1) offs[kNE] = excl + val;
}

// ---------- fill edge lists (de-indirected: store (s,q) / d directly) ----------
__global__ void k_fill(const int* __restrict__ prof_src, const int* __restrict__ prof_dst,
                       const int* __restrict__ pur_src, const int* __restrict__ pur_dst,
                       const int* __restrict__ q_id,
                       const int* __restrict__ offs3, int* __restrict__ cur3,
                       int* __restrict__ plist, int2* __restrict__ list_in,
                       int* __restrict__ list_out) {
  const int* offs_p  = offs3;
  const int* offs_in = offs3 + kAlignNE;
  const int* offs_ou = offs3 + 2 * kAlignNE;
  int* cur_p  = cur3;
  int* cur_in = cur3 + kAlignNE;
  int* cur_ou = cur3 + 2 * kAlignNE;
  int stride = gridDim.x * blockDim.x;
  for (int i = blockIdx.x * blockDim.x + threadIdx.x; i < kEP; i += stride) {
    int d = prof_dst[i];
    plist[offs_p[d] + atomicAdd(&cur_p[d], 1)] = prof_src[i];
  }
  for (int i = blockIdx.x * blockDim.x + threadIdx.x; i < kEU; i += stride) {
    int s = pur_src[i], d = pur_dst[i];
    list_in[offs_in[d] + atomicAdd(&cur_in[d], 1)] = make_int2(s, q_id[i]);
    list_out[offs_ou[s] + atomicAdd(&cur_ou[s], 1)] = d;
  }
}

// ---------- l-part init + inv: e0/out l-cols = entity_l; inv = 1/sqrt(deg_i) ----------
__global__ void k_l_init(const float4* __restrict__ entity_l,
                         const int* __restrict__ offs3,
                         float* __restrict__ inv,
                         float4* __restrict__ e_buf, float4* __restrict__ out) {
  const int* offs_in = offs3 + kAlignNE;
  const int* offs_ou = offs3 + 2 * kAlignNE;
  const long long total = (long long)kNE * 16;
  long long stride = (long long)gridDim.x * blockDim.x;
  for (long long t = (long long)blockIdx.x * blockDim.x + threadIdx.x; t < total;
       t += stride) {
    int v = (int)(t >> 4);
    int c = (int)(t & 15);
    float4 lv = entity_l[v * 16 + c];
    e_buf[(long long)v * kC4 + c] = lv;
    out[(long long)v * kC4 + c] = lv;
    if (c == 0) {
      int deg = (offs_in[v + 1] - offs_in[v]) + (offs_ou[v + 1] - offs_ou[v]);
      inv[v] = 1.0f / sqrtf((float)(deg > 1 ? deg : 1));
    }
  }
}

// ---------- h-part: mean of review rows. 32 lanes <-> one 512B review row ----------
__global__ void k_h_pull(const float4* __restrict__ review_h,
                         const int* __restrict__ plist,
                         const int* __restrict__ offs3,
                         float4* __restrict__ e_buf, float4* __restrict__ out) {
  const int* offs_p = offs3;
  const long long total = (long long)kNE * 32;
  long long stride = (long long)gridDim.x * blockDim.x;
  for (long long t = (long long)blockIdx.x * blockDim.x + threadIdx.x; t < total;
       t += stride) {
    int v = (int)(t >> 5);
    int c = (int)(t & 31);
    int p0 = offs_p[v], p1 = offs_p[v + 1];
    float ax = 0, ay = 0, az = 0, aw = 0;
    for (int j = p0; j < p1; j++) {
      int r = plist[j];
      float4 h = review_h[(long long)r * 32 + c];
      ax += h.x; ay += h.y; az += h.z; aw += h.w;
    }
    float rp = 1.0f / (float)((p1 - p0) > 1 ? (p1 - p0) : 1);
    float4 res = {ax * rp, ay * rp, az * rp, aw * rp};
    long long o = (long long)v * kC4 + 16 + c;
    e_buf[o] = res;
    out[o] = res;
  }
}

// ---------- conv hop. 64 lanes <-> one vertex, 3 floats/lane (192 = 64*3).
// MODE 0: hop1, accumulate q-term separately and WRITE qsum.
// MODE 1: hop2, READ qsum instead of gathering q_e0.
// MODE 2: fallback (ws too small): gather q_e0 every hop, no qsum I/O.
// e_new[v] = inv[v]*(sum_in e[s] + qterm + sum_out e[d]*inv[d]);
// out = (out + e_new) * rdiv ----------
template <int MODE>
__global__ void k_conv(const float* __restrict__ e,
                       const float* __restrict__ q_e0,
                       const int2* __restrict__ list_in,
                       const int* __restrict__ list_out,
                       const int* __restrict__ offs3,
                       const float* __restrict__ inv,
                       float* __restrict__ qsum,
                       float* __restrict__ e_next,
                       float* __restrict__ out,
                       float rdiv) {
  const int* offs_in = offs3 + kAlignNE;
  const int* offs_ou = offs3 + 2 * kAlignNE;
  const long long total = (long long)kNE * 64;
  long long stride = (long long)gridDim.x * blockDim.x;
  for (long long t = (long long)blockIdx.x * blockDim.x + threadIdx.x; t < total;
       t += stride) {
    int v = (int)(t >> 6);          // uniform per wave
    int f = ((int)(t & 63)) * 3;    // 3 floats per lane
    float a0 = 0, a1 = 0, a2 = 0;
    float q0 = 0, q1 = 0, q2 = 0;

    int i0 = offs_in[v], i1 = offs_in[v + 1];
    for (int j = i0; j < i1; j++) {
      int2 sq = list_in[j];
      int s = __builtin_amdgcn_readfirstlane(sq.x);
      const float* er = e + (size_t)s * kD + f;
      a0 += er[0]; a1 += er[1]; a2 += er[2];
      if (MODE == 0 || MODE == 2) {
        int q = __builtin_amdgcn_readfirstlane(sq.y);
        float ivs = inv[s];
        const float* qr = q_e0 + (size_t)q * kD + f;
        q0 += qr[0] * ivs; q1 += qr[1] * ivs; q2 += qr[2] * ivs;
      }
    }

    int o0 = offs_ou[v], o1 = offs_ou[v + 1];
    for (int j = o0; j < o1; j++) {
      int d = __builtin_amdgcn_readfirstlane(list_out[j]);
      float ivd = inv[d];
      const float* er = e + (size_t)d * kD + f;
      a0 += er[0] * ivd; a1 += er[1] * ivd; a2 += er[2] * ivd;
    }

    if (MODE == 0) {
      float* qp = qsum + (size_t)v * kD + f;
      qp[0] = q0; qp[1] = q1; qp[2] = q2;
      a0 += q0; a1 += q1; a2 += q2;
    } else if (MODE == 1) {
      const float* qp = qsum + (size_t)v * kD + f;
      a0 += qp[0]; a1 += qp[1]; a2 += qp[2];
    } else {
      a0 += q0; a1 += q1; a2 += q2;
    }

    float ivv = inv[v];
    float e0 = a0 * ivv, e1 = a1 * ivv, e2 = a2 * ivv;
    float* ep = e_next + (size_t)v * kD + f;
    ep[0] = e0; ep[1] = e1; ep[2] = e2;
    float* op = out + (size_t)v * kD + f;
    op[0] = (op[0] + e0) * rdiv;
    op[1] = (op[1] + e1) * rdiv;
    op[2] = (op[2] + e2) * rdiv;
  }
}

extern "C" void kernel_launch(void* const* d_in, const int* in_sizes, int n_in,
                              void* d_out, int out_size, void* d_ws, size_t ws_size,
                              hipStream_t stream) {
  const float4* entity_l = (const float4*)d_in[0];
  const float4* review_h = (const float4*)d_in[1];
  const float*  query_e0 = (const float*)d_in[2];
  const int* prof_src = (const int*)d_in[3];
  const int* prof_dst = (const int*)d_in[4];
  const int* pur_src  = (const int*)d_in[5];
  const int* pur_dst  = (const int*)d_in[6];
  const int* q_id     = (const int*)d_in[7];

  const size_t row_floats = (size_t)kNE * kD;           // 38.4M floats
  float* B0    = (float*)d_ws;                          // e ping  (153.6 MB)
  float* B1    = B0 + row_floats;                       // e pong  (153.6 MB)
  float* inv   = B1 + row_floats;                       // kAlignNE
  int*   cnt3  = (int*)(inv + kAlignNE);                // 3 x kAlignNE
  int*   cur3  = cnt3 + 3 * kAlignNE;                   // 3 x kAlignNE
  int*   offs3 = cur3 + 3 * kAlignNE;                   // 3 x kAlignNE
  int*   bsum3 = offs3 + 3 * kAlignNE;                  // 3 x kNBlk (pad 4096)
  int*   plist = bsum3 + 4096;                          // 1M
  int2*  list_in = (int2*)(plist + kEP);                // 1M int2
  int*   list_out = (int*)(list_in + kEU);              // 1M
  float* qsum = (float*)(list_out + kEU);               // optional 153.6 MB
  size_t need_with_qsum = (size_t)((char*)(qsum + row_floats) - (char*)d_ws);
  const bool use_qsum = ws_size >= need_with_qsum;      // fixed per process -> graph-safe

  // zero histograms + cursors (contiguous 6*kAlignNE ints)
  hipMemsetAsync(cnt3, 0, 6 * kAlignNE * sizeof(int), stream);

  k_count3<<<grid_for(kEU), TPB, 0, stream>>>(prof_dst, pur_src, pur_dst, cnt3);

  dim3 sg(kNBlk, 3);
  k_scan_a3<<<sg, TPB, 0, stream>>>(cnt3, bsum3);
  k_scan_b3<<<1, 192, 0, stream>>>(bsum3);
  k_scan_c3<<<sg, TPB, 0, stream>>>(cnt3, bsum3, offs3);

  k_fill<<<grid_for(kEU), TPB, 0, stream>>>(prof_src, prof_dst, pur_src, pur_dst,
                                            q_id, offs3, cur3, plist, list_in,
                                            list_out);

  k_l_init<<<grid_for((long long)kNE * 16), TPB, 0, stream>>>(
      entity_l, offs3, inv, (float4*)B0, (float4*)d_out);
  k_h_pull<<<grid_for((long long)kNE * 32), TPB, 0, stream>>>(
      review_h, plist, offs3, (float4*)B0, (float4*)d_out);

  const int cg = grid_for((long long)kNE * 64);
  if (use_qsum) {
    k_conv<0><<<cg, TPB, 0, stream>>>(B0, query_e0, list_in, list_out, offs3, inv,
                                      qsum, B1, (float*)d_out, 1.0f);
    k_conv<1><<<cg, TPB, 0, stream>>>(B1, query_e0, list_in, list_out, offs3, inv,
                                      qsum, B0, (float*)d_out, 1.0f / 3.0f);
  } else {
    k_conv<2><<<cg, TPB, 0, stream>>>(B0, query_e0, list_in, list_out, offs3, inv,
                                      nullptr, B1, (float*)d_out, 1.0f);
    k_conv<2><<<cg, TPB, 0, stream>>>(B1, query_e0, list_in, list_out, offs3, inv,
                                      nullptr, B0, (float*)d_out, 1.0f / 3.0f);
  }
}